// Round 8
// baseline (220.428 us; speedup 1.0000x reference)
//
#include <hip/hip_runtime.h>

// EdgeModel: out = leaky_relu(concat(x_s[src], x_t[tgt], edge_attr, u[batch]) @ W1 + b1) @ W2 + b2
// F_XS=10, F_XT=5, F_E=10, F_U=10 -> concat 35, hidden 10, out 10.
//
// Round 13: software-pipelined tiles (4x256/block) on the R3 structure.
//   R7 post-mortem: dropping NT regressed (FETCH 93->115 MB) -- cacheable streams
//   evict the f16 tables from L2; NT was protecting them. R3 stays best (63.7us).
//   Cycle accounting for R3 now closes: HBM streams ~29us + VALU ~17us + L2
//   gathers ~12us + LDS ~4us ~= 63.7us measured -> the phases are SERIAL
//   (load burst -> compute -> store burst, blocks convoy). Binder = phase
//   serialization, not any saturated pipe.
//   Fix: per-block 4-tile pipeline, double-buffered row_lds:
//     stage attr(t)->buf p | sync | coop-store tile t-1 from buf p^1 |
//     issue gathers(t) | PREFETCH idx/attr(t+1) | compute(t) | out rows->buf p | sync
//   Every barrier drain happens >= 1 compute phase after the drained loads were
//   issued -> drains are free; HBM issue is continuous. idx becomes direct
//   per-thread dwords (already coalesced; kills idx_lds + its dependency).
//   launch_bounds(256,4): VGPR cap 128 so prefetch regs stay live (R4 lesson).
//   Kept: NT stream loads, plain stores, f16 L2-resident tables, attr-first MLP.

#define F_XS 10
#define F_XT 5
#define F_E  10
#define F_U  10
#define F_IN 35
#define BLOCK 256
#define TILES 4

typedef float vf4 __attribute__((ext_vector_type(4)));
typedef float vf2 __attribute__((ext_vector_type(2)));
typedef _Float16 f16;

// ---------------- table conversion pass (runs every call, ~5 us) ----------------
__global__ __launch_bounds__(256) void convert_tables_kernel(
    const float* __restrict__ xs, const float* __restrict__ xt, const float* __restrict__ uu,
    f16* __restrict__ xs_h, f16* __restrict__ xt_h, f16* __restrict__ u_h,
    int n_xs_elems, int n_u_elems, int n_t_rows)
{
    const int tid = blockIdx.x * blockDim.x + threadIdx.x;
    if (tid < n_xs_elems) {
        xs_h[tid] = (f16)xs[tid];
    } else if (tid < n_xs_elems + n_u_elems) {
        const int i = tid - n_xs_elems;
        u_h[i] = (f16)uu[i];
    } else {
        const int r = tid - n_xs_elems - n_u_elems;
        if (r < n_t_rows) {
            const float* p = xt + (long long)r * F_XT;
            f16* q = xt_h + (long long)r * 6;
            #pragma unroll
            for (int i = 0; i < 5; ++i) q[i] = (f16)p[i];
            q[5] = (f16)0.f;
        }
    }
}

// ---------------- per-edge math, attr segment FIRST (gathers still in flight) ----------------
__device__ __forceinline__ void compute_edge_attrfirst(
    const f16* __restrict__ s, const f16* __restrict__ t, const f16* __restrict__ uv,
    const float* __restrict__ a,
    const float* __restrict__ W1, const float* __restrict__ b1,
    const float* __restrict__ W2, const float* __restrict__ b2,
    float* __restrict__ o)
{
    float h[F_E];
    #pragma unroll
    for (int j = 0; j < F_E; ++j) h[j] = b1[j];

    #pragma unroll
    for (int k = 0; k < 10; ++k) {          // edge_attr segment, rows 15..24 (LDS-sourced)
        const float x = a[k];
        #pragma unroll
        for (int j = 0; j < F_E; ++j) h[j] = fmaf(x, W1[(15 + k) * F_E + j], h[j]);
    }
    #pragma unroll
    for (int k = 0; k < 10; ++k) {          // x_s segment, rows 0..9
        const float x = (float)s[k];
        #pragma unroll
        for (int j = 0; j < F_E; ++j) h[j] = fmaf(x, W1[k * F_E + j], h[j]);
    }
    #pragma unroll
    for (int k = 0; k < 5; ++k) {           // x_t segment, rows 10..14
        const float x = (float)t[k];
        #pragma unroll
        for (int j = 0; j < F_E; ++j) h[j] = fmaf(x, W1[(10 + k) * F_E + j], h[j]);
    }
    #pragma unroll
    for (int k = 0; k < 10; ++k) {          // u segment, rows 25..34
        const float x = (float)uv[k];
        #pragma unroll
        for (int j = 0; j < F_E; ++j) h[j] = fmaf(x, W1[(25 + k) * F_E + j], h[j]);
    }

    #pragma unroll
    for (int j = 0; j < F_E; ++j) h[j] = (h[j] >= 0.0f) ? h[j] : 0.1f * h[j];

    #pragma unroll
    for (int j = 0; j < F_E; ++j) o[j] = b2[j];
    #pragma unroll
    for (int k = 0; k < F_E; ++k) {
        const float x = h[k];
        #pragma unroll
        for (int j = 0; j < F_E; ++j) o[j] = fmaf(x, W2[k * F_E + j], o[j]);
    }
}

// ---------------- main kernel: 4-tile pipelined, double-buffered LDS ----------------
__global__ __launch_bounds__(256, 4) void edge_model_pipe_kernel(
    const f16*   __restrict__ xs_h,       // [N_S, 10] f16
    const f16*   __restrict__ xt_h,       // [N_T, 6]  f16 (padded)
    const int*   __restrict__ edge_index, // [2, E]
    const float* __restrict__ edge_attr,  // [E, 10]
    const f16*   __restrict__ u_h,        // [B, 10] f16
    const int*   __restrict__ batch_e,    // [E]
    const float* __restrict__ W1,         // [35, 10]
    const float* __restrict__ b1,         // [10]
    const float* __restrict__ W2,         // [10, 10]
    const float* __restrict__ b2,         // [10]
    float*       __restrict__ out,        // [E, 10]
    int E)
{
    __shared__ __align__(16) float row_lds[2][10 * BLOCK];   // 2 x 10 KiB

    const int tid = threadIdx.x;
    const long long base0 = (long long)blockIdx.x * (BLOCK * TILES);

    if (base0 + BLOCK * TILES <= E) {
        // ---- prologue: issue tile-0 streams (un-overlapped once per block) ----
        const long long e0 = base0 + tid;
        int src = __builtin_nontemporal_load(edge_index + e0);          // coalesced dwords
        int tgt = __builtin_nontemporal_load(edge_index + E + e0);
        int be  = __builtin_nontemporal_load(batch_e + e0);
        const vf4* pa0 = (const vf4*)(edge_attr + base0 * F_E);         // 640 x4 slots/tile
        vf4 A0 = __builtin_nontemporal_load(pa0 + tid);
        vf4 A1 = __builtin_nontemporal_load(pa0 + tid + 256);
        vf4 A2{};
        if (tid < 128) A2 = __builtin_nontemporal_load(pa0 + tid + 512);

        #pragma unroll
        for (int t = 0; t < TILES; ++t) {
            const int p = t & 1;
            float* rw = row_lds[p];

            // s0: stage attr(t) into buf p (counted wait on attr regs only)
            *(vf4*)(rw + 4 * tid)         = A0;
            *(vf4*)(rw + 4 * (tid + 256)) = A1;
            if (tid < 128) *(vf4*)(rw + 4 * (tid + 512)) = A2;
            __syncthreads();   // drains: prefetch(t) (issued 1 compute phase ago) -> free

            // s1.5: coop store tile t-1 from buf p^1 (full 64B lines)
            if (t > 0) {
                const float* rv = row_lds[p ^ 1];
                float* po = out + (base0 + (long long)(t - 1) * BLOCK) * F_E;
                *(vf4*)(po + 4 * tid)         = *(const vf4*)(rv + 4 * tid);
                *(vf4*)(po + 4 * (tid + 256)) = *(const vf4*)(rv + 4 * (tid + 256));
                if (tid < 128)
                    *(vf4*)(po + 4 * (tid + 512)) = *(const vf4*)(rv + 4 * (tid + 512));
            }

            // s2: issue divergent gathers(t) (idx already in regs — no barrier dep)
            f16 s[10];  __builtin_memcpy(s,   xs_h + (long long)src * 10, 20);
            f16 tt_[8]; __builtin_memcpy(tt_, xt_h + (long long)tgt * 6, 16);
            f16 uv[10]; __builtin_memcpy(uv,  u_h  + (long long)be  * 10, 20);

            // s3: prefetch tile t+1 streams (land during compute; drained at s6 for free)
            if (t + 1 < TILES) {
                const long long e1 = base0 + (long long)(t + 1) * BLOCK + tid;
                src = __builtin_nontemporal_load(edge_index + e1);
                tgt = __builtin_nontemporal_load(edge_index + E + e1);
                be  = __builtin_nontemporal_load(batch_e + e1);
                const vf4* pa = (const vf4*)(edge_attr + (base0 + (long long)(t + 1) * BLOCK) * F_E);
                A0 = __builtin_nontemporal_load(pa + tid);
                A1 = __builtin_nontemporal_load(pa + tid + 256);
                if (tid < 128) A2 = __builtin_nontemporal_load(pa + tid + 512);
            }

            // s4: own attr row (5x ds_read_b64) + MLP (gathers drain under attr FMAs)
            float af[F_E];
            #pragma unroll
            for (int q = 0; q < 5; ++q) {
                const vf2 v = *(const vf2*)(rw + 10 * tid + 2 * q);
                af[2 * q]     = v.x;
                af[2 * q + 1] = v.y;
            }
            float o[F_E];
            compute_edge_attrfirst(s, tt_, uv, af, W1, b1, W2, b2, o);

            // s5: out row -> own slot of buf p (same-thread words: no sync needed)
            #pragma unroll
            for (int q = 0; q < 5; ++q) {
                vf2 v; v.x = o[2 * q]; v.y = o[2 * q + 1];
                *(vf2*)(rw + 10 * tid + 2 * q) = v;
            }
            __syncthreads();   // drains: prefetch(t+1)/stores(t-1), both ~1 compute phase old -> free
        }

        // epilogue: store last tile
        {
            const float* rv = row_lds[(TILES - 1) & 1];
            float* po = out + (base0 + (long long)(TILES - 1) * BLOCK) * F_E;
            *(vf4*)(po + 4 * tid)         = *(const vf4*)(rv + 4 * tid);
            *(vf4*)(po + 4 * (tid + 256)) = *(const vf4*)(rv + 4 * (tid + 256));
            if (tid < 128)
                *(vf4*)(po + 4 * (tid + 512)) = *(const vf4*)(rv + 4 * (tid + 512));
        }
    } else {
        // ---- tail block (block-uniform branch; no barriers) ----
        for (int t = 0; t < TILES; ++t) {
            const long long e = base0 + (long long)t * BLOCK + tid;
            if (e >= E) continue;
            const int src = edge_index[e];
            const int tgt = edge_index[E + e];
            const int be  = batch_e[e];
            f16 s1[10], t1[8], u1[10];
            __builtin_memcpy(s1, xs_h + (long long)src * 10, 20);
            __builtin_memcpy(t1, xt_h + (long long)tgt * 6, 16);
            __builtin_memcpy(u1, u_h  + (long long)be  * 10, 20);
            float a1[F_E];
            #pragma unroll
            for (int k = 0; k < F_E; ++k) a1[k] = edge_attr[e * F_E + k];
            float o1[F_E];
            compute_edge_attrfirst(s1, t1, u1, a1, W1, b1, W2, b2, o1);
            #pragma unroll
            for (int j = 0; j < F_E; ++j) out[e * F_E + j] = o1[j];
        }
    }
}

// ---------------- fallback: f32 path (if ws too small) ----------------
__global__ __launch_bounds__(256) void edge_model_f32_kernel(
    const float* __restrict__ x_s, const float* __restrict__ x_t,
    const int*   __restrict__ edge_index, const float* __restrict__ edge_attr,
    const float* __restrict__ u, const int* __restrict__ batch_e,
    const float* __restrict__ W1, const float* __restrict__ b1,
    const float* __restrict__ W2, const float* __restrict__ b2,
    float* __restrict__ out, int E)
{
    const int e = blockIdx.x * blockDim.x + threadIdx.x;
    if (e >= E) return;
    const int src = edge_index[e];
    const int tgt = edge_index[E + e];
    const int be  = batch_e[e];

    float in[F_IN];
    __builtin_memcpy(in,      x_s + (long long)src * F_XS, 40);
    __builtin_memcpy(in + 10, x_t + (long long)tgt * F_XT, 20);
    const float* pe = edge_attr + (long long)e * F_E;
    vf4 a0 = *(const vf4*)(pe);
    vf4 a1 = *(const vf4*)(pe + 4);
    vf2 a2 = *(const vf2*)(pe + 8);
    in[15]=a0.x; in[16]=a0.y; in[17]=a0.z; in[18]=a0.w;
    in[19]=a1.x; in[20]=a1.y; in[21]=a1.z; in[22]=a1.w;
    in[23]=a2.x; in[24]=a2.y;
    __builtin_memcpy(in + 25, u + (long long)be * F_U, 40);

    float h[F_E];
    #pragma unroll
    for (int j = 0; j < F_E; ++j) h[j] = b1[j];
    #pragma unroll
    for (int k = 0; k < F_IN; ++k) {
        const float a = in[k];
        #pragma unroll
        for (int j = 0; j < F_E; ++j) h[j] = fmaf(a, W1[k * F_E + j], h[j]);
    }
    #pragma unroll
    for (int j = 0; j < F_E; ++j) h[j] = (h[j] >= 0.0f) ? h[j] : 0.1f * h[j];

    float o[F_E];
    #pragma unroll
    for (int j = 0; j < F_E; ++j) o[j] = b2[j];
    #pragma unroll
    for (int k = 0; k < F_E; ++k) {
        const float a = h[k];
        #pragma unroll
        for (int j = 0; j < F_E; ++j) o[j] = fmaf(a, W2[k * F_E + j], o[j]);
    }
    float* po = out + (long long)e * F_E;
    vf4 w0; w0.x=o[0]; w0.y=o[1]; w0.z=o[2]; w0.w=o[3];
    vf4 w1; w1.x=o[4]; w1.y=o[5]; w1.z=o[6]; w1.w=o[7];
    vf2 w2; w2.x=o[8]; w2.y=o[9];
    *(vf4*)(po)     = w0;
    *(vf4*)(po + 4) = w1;
    *(vf2*)(po + 8) = w2;
}

extern "C" void kernel_launch(void* const* d_in, const int* in_sizes, int n_in,
                              void* d_out, int out_size, void* d_ws, size_t ws_size,
                              hipStream_t stream) {
    const float* x_s        = (const float*)d_in[0];
    const float* x_t        = (const float*)d_in[1];
    const int*   edge_index = (const int*)  d_in[2];
    const float* edge_attr  = (const float*)d_in[3];
    const float* u          = (const float*)d_in[4];
    const int*   batch_e    = (const int*)  d_in[5];
    const float* W1         = (const float*)d_in[6];
    const float* b1         = (const float*)d_in[7];
    const float* W2         = (const float*)d_in[8];
    const float* b2         = (const float*)d_in[9];
    float*       out        = (float*)d_out;

    const int E   = in_sizes[5];           // batch_e is [E]
    const int N_S = in_sizes[0] / F_XS;
    const int N_T = in_sizes[1] / F_XT;
    const int Bn  = in_sizes[4] / F_U;

    // ws layout (16B-aligned regions): xs_h [N_S*10 f16] | xt_h [N_T*6 f16 + 16B slack] | u_h [Bn*10 f16]
    const size_t xs_bytes = (size_t)N_S * 10 * sizeof(f16);
    const size_t xs_off   = 0;
    const size_t xt_off   = (xs_off + xs_bytes + 15) & ~(size_t)15;
    const size_t xt_bytes = (size_t)N_T * 6 * sizeof(f16) + 16;  // +16: dwordx4 slack on last row
    const size_t u_off    = (xt_off + xt_bytes + 15) & ~(size_t)15;
    const size_t u_bytes  = (size_t)Bn * 10 * sizeof(f16);
    const size_t need     = u_off + u_bytes;

    const int block = BLOCK;

    if (ws_size >= need) {
        f16* xs_h = (f16*)((char*)d_ws + xs_off);
        f16* xt_h = (f16*)((char*)d_ws + xt_off);
        f16* u_h  = (f16*)((char*)d_ws + u_off);

        const int n_xs = N_S * 10, n_u = Bn * 10;
        const int conv_threads = n_xs + n_u + N_T;
        convert_tables_kernel<<<(conv_threads + block - 1) / block, block, 0, stream>>>(
            x_s, x_t, u, xs_h, xt_h, u_h, n_xs, n_u, N_T);

        const int edges_per_block = block * TILES;
        const int grid_e = (int)(((long long)E + edges_per_block - 1) / edges_per_block);
        edge_model_pipe_kernel<<<grid_e, block, 0, stream>>>(
            xs_h, xt_h, edge_index, edge_attr, u_h, batch_e, W1, b1, W2, b2, out, E);
    } else {
        const int grid_e = (E + block - 1) / block;
        edge_model_f32_kernel<<<grid_e, block, 0, stream>>>(
            x_s, x_t, edge_index, edge_attr, u, batch_e, W1, b1, W2, b2, out, E);
    }
}